// Round 11
// baseline (171.376 us; speedup 1.0000x reference)
//
#include <hip/hip_runtime.h>
#include <math.h>

#define HW    9216
#define KJ    17
#define BATCH 128
#define TOPK  8
#define NROW  (BATCH * KJ)   // 2176

typedef float f32x4 __attribute__((ext_vector_type(4)));  // clang vector:
// __builtin_nontemporal_load rejects HIP_vector_type (class) pointers.

// R11: hybrid FLIPPED — outp cached, tgt nt. Evidence chain: R8 (nt both)
// k1 60->46us (removing our L2/L3 allocations that contended with the
// harness's in-window 320.9MB/dispatch re-poison fills). R10 (tgt cached)
// REGRESSED to 171.3 -> tgt is NOT L3-resident; its cached misses
// re-allocated 80MB and resurrected fill contention. But pre-R8 FETCH was
// always exactly ONE tensor (78MB) -> one input IS resident at kernel
// start. Only remaining candidate: outp. Fill writes 320.9MB > 256MB L3,
// so the last-written range survives — consistent with outp in the
// surviving tail. Cached L3 hits: no HBM BW, ~200cy, no allocation on hit.
// Pre-registered: regress>=170 -> revert to R8 both-nt and declare plateau.
__global__ __launch_bounds__(256, 6) void per_joint_mse(
    const float* __restrict__ outp, const float* __restrict__ tgt,
    const float* __restrict__ tw, float* __restrict__ pj)
{
    const int row = blockIdx.x;            // b*KJ + k
    const f32x4* o4 = (const f32x4*)(outp + (size_t)row * HW);
    const f32x4* t4 = (const f32x4*)(tgt  + (size_t)row * HW);
    const int tid = threadIdx.x;

    // Prologue: fill the 4-deep rotating buffer (8 loads in flight).
    f32x4 ob[4], tb[4];
#pragma unroll
    for (int j = 0; j < 4; ++j) {
        ob[j] = o4[tid + j * 256];                               // cached (L3-hit?)
        tb[j] = __builtin_nontemporal_load(t4 + tid + j * 256);  // nt stream
    }

    float acc = 0.f;
    // Steady state: consume slot (j&3), immediately refill with load j+4.
    // Fully unrolled -> all ring indices compile-time constant (no scratch).
#pragma unroll
    for (int j = 0; j < 9; ++j) {
        const f32x4 o = ob[j & 3];
        const f32x4 t = tb[j & 3];
        if (j + 4 < 9) {
            ob[j & 3] = o4[tid + (j + 4) * 256];
            tb[j & 3] = __builtin_nontemporal_load(t4 + tid + (j + 4) * 256);
        }
        float d;
        d = o.x - t.x; acc = fmaf(d, d, acc);
        d = o.y - t.y; acc = fmaf(d, d, acc);
        d = o.z - t.z; acc = fmaf(d, d, acc);
        d = o.w - t.w; acc = fmaf(d, d, acc);
    }

    // wave64 shuffle reduce
#pragma unroll
    for (int off = 32; off > 0; off >>= 1)
        acc += __shfl_down(acc, off, 64);

    __shared__ float smem[4];
    if ((tid & 63) == 0) smem[tid >> 6] = acc;
    __syncthreads();
    if (tid == 0) {
        const float w = tw[row];
        const float tot = smem[0] + smem[1] + smem[2] + smem[3];
        pj[row] = tot * w * w * (1.0f / (float)HW);
    }
}

// Kernel 2: per-sample top-8-of-17, then mean over batch. 1 block, 128
// threads. Measured-free vs the ~96us of in-window harness re-poison fills
// (fills write 320.9MB each at 6.7 TB/s — untouchable fixed residue).
__global__ __launch_bounds__(128) void ohkm_reduce(
    const float* __restrict__ pj, float* __restrict__ result)
{
    const int b = threadIdx.x;   // 0..127 — one sample per thread
    float v[KJ];
#pragma unroll
    for (int k = 0; k < KJ; ++k) v[k] = pj[b * KJ + k];

    float s = 0.f;
#pragma unroll
    for (int t = 0; t < TOPK; ++t) {
        float m = v[0];
#pragma unroll
        for (int k = 1; k < KJ; ++k) m = fmaxf(m, v[k]);
        s += m;
        // remove exactly the FIRST element equal to m (tie-safe top_k semantics)
        bool removed = false;
#pragma unroll
        for (int k = 0; k < KJ; ++k) {
            const bool hit = (!removed) && (v[k] == m);
            v[k] = hit ? -INFINITY : v[k];
            removed = removed || hit;
        }
    }

    // 128 threads = 2 waves
#pragma unroll
    for (int off = 32; off > 0; off >>= 1)
        s += __shfl_down(s, off, 64);

    __shared__ float smem[2];
    if ((b & 63) == 0) smem[b >> 6] = s;
    __syncthreads();
    if (b == 0)
        result[0] = (smem[0] + smem[1]) * (1.0f / (float)(BATCH * TOPK));
}

extern "C" void kernel_launch(void* const* d_in, const int* in_sizes, int n_in,
                              void* d_out, int out_size, void* d_ws, size_t ws_size,
                              hipStream_t stream) {
    const float* outp = (const float*)d_in[0];   // [128,17,96,96]
    const float* tgt  = (const float*)d_in[1];   // [128,17,96,96]
    const float* tw   = (const float*)d_in[2];   // [128,17,1]
    float* result = (float*)d_out;               // scalar
    float* pj = (float*)d_ws;                    // [2176] per-joint MSE

    per_joint_mse<<<NROW, 256, 0, stream>>>(outp, tgt, tw, pj);
    ohkm_reduce<<<1, 128, 0, stream>>>(pj, result);
}

// Round 12
// 164.874 us; speedup vs baseline: 1.0394x; 1.0394x over previous
//
#include <hip/hip_runtime.h>
#include <math.h>

#define HW     9216
#define KJ     17
#define BATCH  128
#define TOPK   8
#define NROW   (BATCH * KJ)      // 2176
#define CHUNK  3                 // chunk-blocks per row
#define CFLOAT (HW / CHUNK)      // 3072 floats per chunk (12 KB, f4-aligned)

typedef float f32x4 __attribute__((ext_vector_type(4)));  // clang vector:
// __builtin_nontemporal_load rejects HIP_vector_type (class) pointers.

// R12 = exact revert to R8 (best measured: 163.5us total, k1 ~46us).
// FINAL. Evidence ledger:
//  - Structural axis (pre- and post-nt): ILP 2..18, occupancy 31-58%, grid
//    1088..6528, +-barriers, ring vs volley — ALL null. Not issue-bound.
//  - nt-both (this kernel): k1 60 -> ~46us. Mechanism: nt still HITS the
//    L3-resident dirty fill data (FETCH 78MB < 160.4MB read) but never
//    allocates -> no dirty-line evictions/writebacks of the harness's
//    320.9MB in-window poison fill (L3 is 256MB; fill wraps it).
//  - Hybrid cached/nt per tensor, both directions (R10/R11): both +7.8us.
//    The surviving L3 tail spans parts of BOTH tensors; any cached stream
//    partially miss-allocates and resurrects writeback traffic. nt-both is
//    the bracketed optimum of the policy axis.
//  - Ceiling: k1 demand-reads at 3.48 TB/s. m13 copy read-side ~3.15 TB/s;
//    fill write-only 6.7 TB/s. No demonstrated demand-read on this chip
//    exceeds ~3.5 TB/s — we are at/above the read-path ceiling.
//  - Residue: ~113us of in-window harness re-poison fills (6.7 TB/s,
//    untouchable) + ~4us k2 (measured-free; R4 fusion attempt regressed).
__global__ __launch_bounds__(256, 6) void per_joint_partial(
    const float* __restrict__ outp, const float* __restrict__ tgt,
    float* __restrict__ pj3)
{
    const int g   = blockIdx.x;          // row * CHUNK + c
    const int row = g / CHUNK;
    const int c   = g - row * CHUNK;
    const size_t base = (size_t)row * HW + (size_t)c * CFLOAT;
    const f32x4* o4 = (const f32x4*)(outp + base);
    const f32x4* t4 = (const f32x4*)(tgt  + base);
    const int tid = threadIdx.x;

    // 3 float4 per tensor per thread — all 6 loads issued up front, nt policy.
    f32x4 o0 = __builtin_nontemporal_load(o4 + tid);
    f32x4 t0 = __builtin_nontemporal_load(t4 + tid);
    f32x4 o1 = __builtin_nontemporal_load(o4 + tid + 256);
    f32x4 t1 = __builtin_nontemporal_load(t4 + tid + 256);
    f32x4 o2 = __builtin_nontemporal_load(o4 + tid + 512);
    f32x4 t2 = __builtin_nontemporal_load(t4 + tid + 512);

    float acc = 0.f;
    float d;
    d = o0.x - t0.x; acc = fmaf(d, d, acc);
    d = o0.y - t0.y; acc = fmaf(d, d, acc);
    d = o0.z - t0.z; acc = fmaf(d, d, acc);
    d = o0.w - t0.w; acc = fmaf(d, d, acc);
    d = o1.x - t1.x; acc = fmaf(d, d, acc);
    d = o1.y - t1.y; acc = fmaf(d, d, acc);
    d = o1.z - t1.z; acc = fmaf(d, d, acc);
    d = o1.w - t1.w; acc = fmaf(d, d, acc);
    d = o2.x - t2.x; acc = fmaf(d, d, acc);
    d = o2.y - t2.y; acc = fmaf(d, d, acc);
    d = o2.z - t2.z; acc = fmaf(d, d, acc);
    d = o2.w - t2.w; acc = fmaf(d, d, acc);

    // wave64 shuffle reduce
#pragma unroll
    for (int off = 32; off > 0; off >>= 1)
        acc += __shfl_down(acc, off, 64);

    __shared__ float smem[4];
    if ((tid & 63) == 0) smem[tid >> 6] = acc;
    __syncthreads();
    if (tid == 0)
        pj3[g] = smem[0] + smem[1] + smem[2] + smem[3];   // raw partial SSD
}

// Kernel 2: sum 3 partials per row, apply w^2/HW, top-8-of-17, batch mean.
// 1 block, 128 threads. ~26 KB reads: measured-free vs the ~113us fixed
// harness residue (R4 proved removing k2 doesn't shrink the residue).
__global__ __launch_bounds__(128) void ohkm_reduce(
    const float* __restrict__ pj3, const float* __restrict__ tw,
    float* __restrict__ result)
{
    const int b = threadIdx.x;   // 0..127
    float v[KJ];
#pragma unroll
    for (int k = 0; k < KJ; ++k) {
        const int r = b * KJ + k;
        const float s3 = pj3[r * CHUNK] + pj3[r * CHUNK + 1] + pj3[r * CHUNK + 2];
        const float w  = tw[r];
        v[k] = s3 * w * w * (1.0f / (float)HW);
    }

    float s = 0.f;
#pragma unroll
    for (int t = 0; t < TOPK; ++t) {
        float m = v[0];
#pragma unroll
        for (int k = 1; k < KJ; ++k) m = fmaxf(m, v[k]);
        s += m;
        // remove exactly the FIRST element equal to m (tie-safe top_k semantics)
        bool removed = false;
#pragma unroll
        for (int k = 0; k < KJ; ++k) {
            const bool hit = (!removed) && (v[k] == m);
            v[k] = hit ? -INFINITY : v[k];
            removed = removed || hit;
        }
    }

    // 128 threads = 2 waves
#pragma unroll
    for (int off = 32; off > 0; off >>= 1)
        s += __shfl_down(s, off, 64);

    __shared__ float smem[2];
    if ((b & 63) == 0) smem[b >> 6] = s;
    __syncthreads();
    if (b == 0)
        result[0] = (smem[0] + smem[1]) * (1.0f / (float)(BATCH * TOPK));
}

extern "C" void kernel_launch(void* const* d_in, const int* in_sizes, int n_in,
                              void* d_out, int out_size, void* d_ws, size_t ws_size,
                              hipStream_t stream) {
    const float* outp = (const float*)d_in[0];   // [128,17,96,96]
    const float* tgt  = (const float*)d_in[1];   // [128,17,96,96]
    const float* tw   = (const float*)d_in[2];   // [128,17,1]
    float* result = (float*)d_out;               // scalar
    float* pj3 = (float*)d_ws;                   // [NROW*CHUNK] partial SSDs

    per_joint_partial<<<NROW * CHUNK, 256, 0, stream>>>(outp, tgt, pj3);
    ohkm_reduce<<<1, 128, 0, stream>>>(pj3, tw, result);
}